// Round 15
// baseline (227.892 us; speedup 1.0000x reference)
//
#include <hip/hip_runtime.h>
#include <hip/hip_bf16.h>
#include <stdint.h>

// Fused causal attention block: qkv proj -> flash attention -> out proj.
// B=4 T=2048 C=1024 H=16 HD=64.  All MFMA 16x16x32 bf16, fp32 accum.
// Q pre-scaled by 0.125*log2(e); base-2 softmax via raw v_exp_f32; T13.
// attn: T12 swapped-QK^T in-register softmax + 3-buf counted-vmcnt pipeline.
// qkv GEMM (R15): 256^2 tile, BK=64, 4-phase intra-iteration pipeline
// (T3-style): 1 barrier + 1 vmcnt per K-tile, phases interleave
// {gload-issue | ds_read | 16 MFMA} with no intra-iteration barriers.

typedef __attribute__((ext_vector_type(8))) short short8;
typedef __attribute__((ext_vector_type(4))) float f32x4;
typedef __attribute__((ext_vector_type(4))) float float4v;
typedef __attribute__((ext_vector_type(4))) unsigned short ushort4v;
typedef __attribute__((ext_vector_type(4))) unsigned int u32x4;

#define AS1 __attribute__((address_space(1)))
#define AS3 __attribute__((address_space(3)))

#if __has_builtin(__builtin_amdgcn_exp2f)
#define EXP2(x) __builtin_amdgcn_exp2f(x)
#else
#define EXP2(x) __expf((x) * 0.69314718f)
#endif

static __device__ __forceinline__ void gload_lds16(const void* g, void* l) {
  __builtin_amdgcn_global_load_lds((const AS1 void*)g, (AS3 void*)l, 16, 0, 0);
}

// ---------------- dtype detect ----------------
__global__ void k_detect(const unsigned int* __restrict__ x, int* __restrict__ flag) {
  __shared__ int sm[256];
  int c = 0;
  for (int i = 0; i < 8; ++i) {
    unsigned int v = x[threadIdx.x * 8 + i];
    unsigned int e = (v >> 7) & 0xffu;
    if (e >= 110u && e <= 140u) c++;
  }
  sm[threadIdx.x] = c;
  __syncthreads();
  if (threadIdx.x == 0) {
    int t = 0;
    for (int i = 0; i < 256; ++i) t += sm[i];
    *flag = (t > 1024) ? 1 : 0;   // 1 = inputs are bf16, 0 = fp32
  }
}

// ---------------- fused convert: x | wqkv | wo -> contiguous bf16 ws ----------------
__global__ void k_convert3(const void* __restrict__ xs, const void* __restrict__ wqs,
                           const void* __restrict__ wos, unsigned short* __restrict__ out,
                           const int* __restrict__ flag) {
  const int f = *flag;
  const int stride = gridDim.x * blockDim.x;
  for (int v = blockIdx.x * blockDim.x + threadIdx.x; v < 3145728; v += stride) {
    const int i = v * 4;
    const void* src; int j;
    if (i < 8388608)        { src = xs;  j = i; }
    else if (i < 11534336)  { src = wqs; j = i - 8388608; }
    else                    { src = wos; j = i - 11534336; }
    ushort4v r;
    if (f) {
      r = *(const ushort4v*)((const unsigned short*)src + j);
    } else {
      float4v fv = *(const float4v*)((const float*)src + j);
#pragma unroll
      for (int e = 0; e < 4; e++) {
        __hip_bfloat16 h = __float2bfloat16(fv[e]);
        r[e] = *(unsigned short*)&h;
      }
    }
    *(ushort4v*)(out + i) = r;
  }
}

// ---------------- stage 1: QKV GEMM (256^2, BK=64, 4-phase pipeline) ----------------
// 8 waves (2M x 4N), wave output 128x64, acc[8][4]. 2 LDS dbuf (128KB).
// Iteration kt: vmcnt(0, own prefetch) -> barrier -> 4 phases:
//   phase q: [q<2: issue 4 gload_lds for tile kt+1 into buf^1]
//            [q==0: 8 b-frag ds_reads] + 4 a-frag ds_reads (rows 2q,2q+1)
//            lgkmcnt(0); sched_barrier; setprio(1); 16 MFMA; setprio(0)
// No intra-iteration barriers: read-buf immutable, writes target other buf
// (all waves finished reading it before this iteration's top barrier).
// LDS chunk swizzle: stored pos p of row r holds global chunk p ^ (r&7);
// staged via pre-swizzled source col (dest linear, rule 21).
__global__ __launch_bounds__(512) void k_gemm_qkv(
    const __hip_bfloat16* __restrict__ X, const __hip_bfloat16* __restrict__ W,
    __hip_bfloat16* __restrict__ qo, __hip_bfloat16* __restrict__ ko,
    __hip_bfloat16* __restrict__ vto) {
  __shared__ __align__(16) __hip_bfloat16 As[2][256 * 64];
  __shared__ __align__(16) __hip_bfloat16 Bs[2][256 * 64];
  const int tid = threadIdx.x;
  const int lane = tid & 63;
  const int wid = tid >> 6;
  const int wm = wid & 1, wn = wid >> 1;
  const int lr = lane & 15, lk = lane >> 4;

  // XCD-bijective swizzle over 384 blocks (384 % 8 == 0)
  const int bid = blockIdx.x;
  const int swz = (bid & 7) * 48 + (bid >> 3);
  const int m0 = (swz & 31) * 256;
  const int n0 = (swz >> 5) * 256;

  // staging: 2048 chunks of 16B per 256x64 tile; thread covers 4 (j=0..3)
  const int srow = tid >> 3;                       // row within 64-row group
  const int schunk = ((tid & 7) ^ (srow & 7)) * 8; // pre-swizzled src col
  const int sdst = (tid & ~63) * 16;               // wave-uniform dest byte

  // per-lane read offsets (bytes within one 32KB buffer)
  int aoff[2], boff[2];
#pragma unroll
  for (int ks = 0; ks < 2; ks++) {
    const int px = (((ks * 4 + lk) ^ (lr & 7)) * 16);
    aoff[ks] = (wm * 128 + lr) * 128 + px;
    boff[ks] = (wn * 64 + lr) * 128 + px;
  }

  const f32x4 fzero = {0.f, 0.f, 0.f, 0.f};
  f32x4 acc[8][4];
#pragma unroll
  for (int i = 0; i < 8; i++)
#pragma unroll
    for (int j = 0; j < 4; j++) acc[i][j] = fzero;

#define QSTG(buf, kt2, j)                                                           \
  gload_lds16(X + (size_t)(m0 + (j) * 64 + srow) * 1024 + (kt2) * 64 + schunk,      \
              (void*)((char*)As + (buf) * 32768 + (j) * 8192 + sdst));              \
  gload_lds16(W + (size_t)(n0 + (j) * 64 + srow) * 1024 + (kt2) * 64 + schunk,      \
              (void*)((char*)Bs + (buf) * 32768 + (j) * 8192 + sdst));

  // prologue: tile 0 into buf 0 (8 loads)
  QSTG(0, 0, 0) QSTG(0, 0, 1) QSTG(0, 0, 2) QSTG(0, 0, 3)

  for (int kt = 0; kt < 16; ++kt) {
    asm volatile("s_waitcnt vmcnt(0)" ::: "memory");
    __builtin_amdgcn_s_barrier();
    __builtin_amdgcn_sched_barrier(0);
    const int buf = kt & 1;
    const int nb = buf ^ 1;
    const char* Ab = (const char*)As + buf * 32768;
    const char* Bb = (const char*)Bs + buf * 32768;

    short8 bf[4][2];
#pragma unroll
    for (int q = 0; q < 4; ++q) {
      if (q == 0 && kt + 1 < 16) { QSTG(nb, kt + 1, 0) QSTG(nb, kt + 1, 1) }
      if (q == 1 && kt + 1 < 16) { QSTG(nb, kt + 1, 2) QSTG(nb, kt + 1, 3) }
      if (q == 0) {
#pragma unroll
        for (int fc = 0; fc < 4; fc++)
#pragma unroll
          for (int ks = 0; ks < 2; ks++)
            bf[fc][ks] = *(const short8*)(Bb + fc * 2048 + boff[ks]);
      }
      short8 af[2][2];
#pragma unroll
      for (int i = 0; i < 2; i++)
#pragma unroll
        for (int ks = 0; ks < 2; ks++)
          af[i][ks] = *(const short8*)(Ab + (2 * q + i) * 2048 + aoff[ks]);
      asm volatile("s_waitcnt lgkmcnt(0)" ::: "memory");
      __builtin_amdgcn_sched_barrier(0);
      __builtin_amdgcn_s_setprio(1);
#pragma unroll
      for (int ks = 0; ks < 2; ks++)
#pragma unroll
        for (int i = 0; i < 2; i++)
#pragma unroll
          for (int fc = 0; fc < 4; fc++)
            acc[2 * q + i][fc] = __builtin_amdgcn_mfma_f32_16x16x32_bf16(
                af[i][ks], bf[fc][ks], acc[2 * q + i][fc], 0, 0, 0);
      __builtin_amdgcn_s_setprio(0);
    }
  }
#undef QSTG

#pragma unroll
  for (int fr = 0; fr < 8; fr++)
#pragma unroll
    for (int fc = 0; fc < 4; fc++)
#pragma unroll
      for (int r = 0; r < 4; r++) {
        const int orow = m0 + wm * 128 + fr * 16 + lk * 4 + r;  // b*T+t
        const int col = n0 + wn * 64 + fc * 16 + lr;            // [0,3072)
        const int s = col >> 10;
        const int rem = col & 1023;
        const int h = rem >> 6, hd = rem & 63;
        const int bb = orow >> 11, t = orow & 2047;
        const size_t bh = (size_t)(bb * 16 + h);
        if (s == 0) {
          // pre-scale Q by 0.125 * log2(e): softmax runs in base-2 domain
          qo[(bh * 2048 + t) * 64 + hd] = __float2bfloat16(acc[fr][fc][r] * 0.18033688f);
        } else if (s == 1) {
          ko[(bh * 2048 + t) * 64 + hd] = __float2bfloat16(acc[fr][fc][r]);
        } else {
          vto[(bh * 64 + hd) * 2048 + t] = __float2bfloat16(acc[fr][fc][r]);
        }
      }
}

// ---------------- stage 2: flash attention (T12 swapped QK^T) ----------------
// 512 blocks x 512 threads (8 waves). Q-tile 256 rows (32/wave). KV tile 64.
// bh = bid&63, p = bid>>6 mapped so CU pairs (e,7-e) have equal totals.
// 3 LDS KV buffers, issue 2 ahead, counted vmcnt(2).
// Swapped QK^T: C = mfma(A=K, B=Q) -> lane owns one q (col=lr), 16 k's.
// A-row permutation f(a,i) = (i>>2)*8 + (a&1)*4 + (i&3) + (a>>1)*32 makes
// lane lk's C regs = exactly k = {lk*8..+7} (+32) -> PV B-frag is built
// IN-LANE (no LDS P, no cross-lane moves). Softmax: 2 shfl per q-group
// (max only); l-sum deferred per-lane to epilogue. O comes out transposed
// -> LDS transpose epilogue (bank-XOR'd) -> coalesced 16B Y stores.
// LDS swizzle F(r) = (r&7) ^ (2*(r>>3) & 7) keeps kb/vb reads uniform.
__global__ __launch_bounds__(512) void k_attn(
    const __hip_bfloat16* __restrict__ Q, const __hip_bfloat16* __restrict__ K,
    const __hip_bfloat16* __restrict__ VT, __hip_bfloat16* __restrict__ Y) {
  __shared__ __align__(16) char smem[49152];   // K bufs 0..2 | V bufs 0..2
  char* smc = smem;
  const int tid = threadIdx.x, lane = tid & 63, wid = tid >> 6;
  const int lr = lane & 15, lk = lane >> 4;

  const int bid = blockIdx.x;
  const int bh = bid & 63;
  const int p = bid >> 6;            // 0..7
  const int e = p & 3;
  const int x = (p < 4) ? p : 7 - e; // CU gets {e, 7-e}: 36 tiles total
  const int q0 = x * 256;
  const int qb = q0 + wid * 32;
  const size_t base = (size_t)bh * 2048 * 64;

  // staging: 512 chunks of 16B per 64x64 tile, source pre-swizzled by F
  const int srow = tid >> 3;                        // 0..63
  const int fs = (srow & 7) ^ ((2 * (srow >> 3)) & 7);
  const int scol = ((tid & 7) ^ fs) * 8;
  const __hip_bfloat16* kg = K + base + scol;
  const __hip_bfloat16* vg = VT + base + (size_t)srow * 2048 + scol;
  const int ldst = (tid & ~63) * 16;                // wave-uniform LDS dest

  // per-lane read offsets (bytes within an 8KB buffer)
  int koff[4][2], voff[4][2], kla[4];
#pragma unroll
  for (int a = 0; a < 4; a++) {
    const int ra = (lr >> 2) * 8 + (a & 1) * 4 + (lr & 3) + (a >> 1) * 32;
    const int fr = (ra & 7) ^ ((2 * (ra >> 3)) & 7);
    kla[a] = lk * 8 + (a & 1) * 4 + (a >> 1) * 32;
#pragma unroll
    for (int ks = 0; ks < 2; ks++)
      koff[a][ks] = ra * 128 + (((ks * 4 + lk) ^ fr) * 16);
  }
#pragma unroll
  for (int df = 0; df < 4; df++) {
    const int rv = df * 16 + lr;
    const int fv = (rv & 7) ^ ((2 * (rv >> 3)) & 7);
#pragma unroll
    for (int ks = 0; ks < 2; ks++)
      voff[df][ks] = rv * 128 + (((ks * 4 + lk) ^ fv) * 16);
  }

  short8 qf[2][2];
#pragma unroll
  for (int qg = 0; qg < 2; qg++)
#pragma unroll
    for (int ks = 0; ks < 2; ks++)
      qf[qg][ks] = *(const short8*)(Q + base + (size_t)(qb + qg * 16 + lr) * 64 + ks * 32 + lk * 8);

  const f32x4 fzero = {0.f, 0.f, 0.f, 0.f};
  f32x4 ot[2][4];                     // O^T accum: row d, col q
  float mrow[2] = {-1e30f, -1e30f}, lrow[2] = {0.f, 0.f};
#pragma unroll
  for (int qg = 0; qg < 2; qg++)
#pragma unroll
    for (int df = 0; df < 4; df++) ot[qg][df] = fzero;

  const int nkv = x * 4 + 4;
  // prologue: stage tiles 0,1 into bufs 0,1
  gload_lds16(kg + (size_t)srow * 64, (void*)(smc + ldst));
  gload_lds16(vg, (void*)(smc + 24576 + ldst));
  gload_lds16(kg + (size_t)(64 + srow) * 64, (void*)(smc + 8192 + ldst));
  gload_lds16(vg + 64, (void*)(smc + 24576 + 8192 + ldst));

  int cur = 0;
  for (int kt = 0; kt < nkv; ++kt) {
    const int k0 = kt * 64;
    if (kt + 1 < nkv) { asm volatile("s_waitcnt vmcnt(2)" ::: "memory"); }
    else              { asm volatile("s_waitcnt vmcnt(0)" ::: "memory"); }
    __builtin_amdgcn_s_barrier();
    __builtin_amdgcn_sched_barrier(0);

    if (k0 <= qb + 31) {   // wave-uniform: skip fully-masked tiles
      const char* kbuf = smc + cur * 8192;
      const char* vbuf = smc + 24576 + cur * 8192;

      f32x4 s[2][4];
#pragma unroll
      for (int qg = 0; qg < 2; qg++)
#pragma unroll
        for (int a = 0; a < 4; a++) s[qg][a] = fzero;

      __builtin_amdgcn_s_setprio(1);
#pragma unroll
      for (int ks = 0; ks < 2; ks++)
#pragma unroll
        for (int a = 0; a < 4; a++) {
          const short8 kb = *(const short8*)(kbuf + koff[a][ks]);
          s[0][a] = __builtin_amdgcn_mfma_f32_16x16x32_bf16(kb, qf[0][ks], s[0][a], 0, 0, 0);
          s[1][a] = __builtin_amdgcn_mfma_f32_16x16x32_bf16(kb, qf[1][ks], s[1][a], 0, 0, 0);
        }
      __builtin_amdgcn_s_setprio(0);

      const bool needmask = (k0 + 63 > qb);
      short8 pb[2][2];

#pragma unroll
      for (int qg = 0; qg < 2; qg++) {
        const int qq = qb + qg * 16 + lr;
        if (needmask) {
#pragma unroll
          for (int a = 0; a < 4; a++)
#pragma unroll
            for (int r = 0; r < 4; r++)
              if (k0 + kla[a] + r > qq) s[qg][a][r] = -1e30f;
        }
        // in-lane max over 16, then 2 shfl across lk groups
        f32x4 m4;
#pragma unroll
        for (int r = 0; r < 4; r++)
          m4[r] = fmaxf(fmaxf(s[qg][0][r], s[qg][1][r]), fmaxf(s[qg][2][r], s[qg][3][r]));
        float mx = fmaxf(fmaxf(m4[0], m4[1]), fmaxf(m4[2], m4[3]));
        mx = fmaxf(mx, __shfl_xor(mx, 16, 64));
        mx = fmaxf(mx, __shfl_xor(mx, 32, 64));
        const float mold = mrow[qg];
        float m;
        if (__all(mx - mold <= 8.f)) {
          m = mold;            // T13 defer: P bounded by 2^8
        } else {
          m = fmaxf(mold, mx);
          const float alpha = EXP2(mold - m);
          lrow[qg] *= alpha;
          mrow[qg] = m;
#pragma unroll
          for (int df = 0; df < 4; df++) ot[qg][df] *= alpha;
        }
        float rs = 0.f;
#pragma unroll
        for (int a = 0; a < 4; a++)
#pragma unroll
          for (int r = 0; r < 4; r++) {
            const float pv = EXP2(s[qg][a][r] - m);
            s[qg][a][r] = pv;
            rs += pv;
          }
        lrow[qg] += rs;        // per-lane partial; cross-lane at epilogue
        // pack PV B-frags: e<4 from block 2ksP, e>=4 from 2ksP+1 (in-lane!)
#pragma unroll
        for (int ksP = 0; ksP < 2; ksP++) {
          short8 w;
#pragma unroll
          for (int ee = 0; ee < 4; ee++) {
            __hip_bfloat16 h0 = __float2bfloat16(s[qg][2 * ksP][ee]);
            __hip_bfloat16 h1 = __float2bfloat16(s[qg][2 * ksP + 1][ee]);
            w[ee] = *(short*)&h0;
            w[4 + ee] = *(short*)&h1;
          }
          pb[qg][ksP] = w;
        }
      }

      // PV: o^T[d][q] += V^T[d][k] * P[k][q]
      __builtin_amdgcn_s_setprio(1);
#pragma unroll
      for (int ks = 0; ks < 2; ks++)
#pragma unroll
        for (int df = 0; df < 4; df++) {
          const short8 vb = *(const short8*)(vbuf + voff[df][ks]);
          ot[0][df] = __builtin_amdgcn_mfma_f32_16x16x32_bf16(vb, pb[0][ks], ot[0][df], 0, 0, 0);
          ot[1][df] = __builtin_amdgcn_mfma_f32_16x16x32_bf16(vb, pb[1][ks], ot[1][df], 0, 0, 0);
        }
      __builtin_amdgcn_s_setprio(0);
    }

    // issue tile kt+2 into buf (cur+2)%3 AFTER compute (3-buf race-freedom)
    if (kt + 2 < nkv) {
      const int kn = (kt + 2) * 64;
      int tb = cur + 2; if (tb >= 3) tb -= 3;
      gload_lds16(kg + (size_t)(kn + srow) * 64, (void*)(smc + tb * 8192 + ldst));
      gload_lds16(vg + kn, (void*)(smc + 24576 + tb * 8192 + ldst));
    }
    cur = (cur + 1 == 3) ? 0 : cur + 1;
  }

  // ---- epilogue: normalize, transpose through LDS, coalesced store ----
  __syncthreads();                      // all waves done with K/V buffers
  unsigned int* Os = (unsigned int*)smc; // 256 rows x 32 u32 = 32 KB
#pragma unroll
  for (int qg = 0; qg < 2; qg++) {
    float ls = lrow[qg];
    ls += __shfl_xor(ls, 16, 64);
    ls += __shfl_xor(ls, 32, 64);
    const float inv = 1.f / ls;
    const int qlocal = wid * 32 + qg * 16 + lr;
    const int sw = (lr & 7) << 2;
#pragma unroll
    for (int df = 0; df < 4; df++)
#pragma unroll
      for (int e2 = 0; e2 < 2; e2++) {
        __hip_bfloat16 h0 = __float2bfloat16(ot[qg][df][2 * e2] * inv);
        __hip_bfloat16 h1 = __float2bfloat16(ot[qg][df][2 * e2 + 1] * inv);
        const unsigned int w = (unsigned int)*(unsigned short*)&h0 |
                               ((unsigned int)*(unsigned short*)&h1 << 16);
        Os[qlocal * 32 + ((df * 8 + lk * 2 + e2) ^ sw)] = w;
      }
  }
  __syncthreads();
  {
    const int qrow = tid >> 1, half = tid & 1, q7 = qrow & 7;
    const int b = bh >> 4, h = bh & 15;
    unsigned int* Yu = (unsigned int*)Y;
    const size_t rowbase = ((size_t)b * 2048 + q0 + qrow) * 512 + h * 32;
#pragma unroll
    for (int g = 0; g < 4; g++) {
      const int cg = half * 4 + g;
      const u32x4 v = *(const u32x4*)(smc + qrow * 128 + ((cg ^ q7) * 16));
      *(u32x4*)(Yu + rowbase + cg * 4) = v;
    }
  }
}

// ---------------- stage 3: output GEMM (8 waves, 3-buf counted vmcnt) ----------------
__global__ __launch_bounds__(512) void k_gemm_out(
    const __hip_bfloat16* __restrict__ X, const __hip_bfloat16* __restrict__ W,
    void* __restrict__ out, const int* __restrict__ flag) {
  __shared__ __align__(16) __hip_bfloat16 As[3][128 * 32];
  __shared__ __align__(16) __hip_bfloat16 Bs[3][128 * 32];
  const int tid = threadIdx.x;
  const int lane = tid & 63;
  const int wid = tid >> 6;
  const int wr = wid & 3, wc = wid >> 2;
  const int lr = lane & 15, lk = lane >> 4;
  const int m0 = blockIdx.x * 128;
  const int n0 = blockIdx.y * 128;
  const int sw = (lr >> 1) & 3;

  const int row = tid >> 2;
  const int ce = ((tid & 3) ^ ((row >> 1) & 3)) * 8;
  const int dst = (tid & ~63) * 8;

  const f32x4 fzero = {0.f, 0.f, 0.f, 0.f};
  f32x4 acc[2][4];
#pragma unroll
  for (int i = 0; i < 2; i++)
#pragma unroll
    for (int j = 0; j < 4; j++) acc[i][j] = fzero;

#define OUT_STAGE(buf, kt2)                                                        \
  {                                                                                \
    const int kk = (kt2) * 32;                                                     \
    gload_lds16(X + (size_t)(m0 + row) * 1024 + kk + ce, (void*)(As[buf] + dst));  \
    gload_lds16(W + (size_t)(n0 + row) * 1024 + kk + ce, (void*)(Bs[buf] + dst));  \
  }

  OUT_STAGE(0, 0)
  OUT_STAGE(1, 1)

  int cur = 0;
  for (int kt = 0; kt < 32; ++kt) {
    if (kt + 1 < 32) { asm volatile("s_waitcnt vmcnt(2)" ::: "memory"); }
    else             { asm volatile("s_waitcnt vmcnt(0)" ::: "memory"); }
    __builtin_amdgcn_s_barrier();
    __builtin_amdgcn_sched_barrier(0);

    short8 a[2], b[4];
#pragma unroll
    for (int i = 0; i < 2; i++) a[i] = *(const short8*)(As[cur] + (wr * 32 + i * 16 + lr) * 32 + ((lk ^ sw) * 8));
#pragma unroll
    for (int i = 0; i < 4; i++) b[i] = *(const short8*)(Bs[cur] + (wc * 64 + i * 16 + lr) * 32 + ((lk ^ sw) * 8));
#pragma unroll
    for (int mf = 0; mf < 2; mf++)
#pragma unroll
      for (int nf = 0; nf < 4; nf++)
        acc[mf][nf] = __builtin_amdgcn_mfma_f32_16x16x32_bf16(a[mf], b[nf], acc[mf][nf], 0, 0, 0);

    if (kt + 2 < 32) {
      int tb = cur + 2; if (tb >= 3) tb -= 3;
      OUT_STAGE(tb, kt + 2)
    }
    cur = (cur + 1 == 3) ? 0 : cur + 1;
  }
#undef OUT_STAGE

  const int f = *flag;
#pragma unroll
  for (int mf = 0; mf < 2; mf++)
#pragma unroll
    for (int nf = 0; nf < 4; nf++)
#pragma unroll
      for (int r = 0; r < 4; r++) {
        const int orow = m0 + wr * 32 + mf * 16 + lk * 4 + r;
        const int col = n0 + wc * 64 + nf * 16 + lr;
        const size_t oi = (size_t)orow * 1024 + col;
        if (f) ((__hip_bfloat16*)out)[oi] = __float2bfloat16(acc[mf][nf][r]);
        else   ((float*)out)[oi] = acc[mf][nf][r];
      }
}

// ---------------- launch ----------------
extern "C" void kernel_launch(void* const* d_in, const int* in_sizes, int n_in,
                              void* d_out, int out_size, void* d_ws, size_t ws_size,
                              hipStream_t stream) {
  const void* x = d_in[0];     // [4,2048,1024]
  const void* wqkv = d_in[1];  // [3072,1024]
  const void* wo = d_in[2];    // [1024,1024]

  char* ws = (char*)d_ws;
  int* flag = (int*)ws;
  __hip_bfloat16* xb    = (__hip_bfloat16*)(ws + 256);
  __hip_bfloat16* wqkvb = xb + 8388608;
  __hip_bfloat16* wob   = wqkvb + 3145728;
  __hip_bfloat16* qws   = wob + 1048576;
  __hip_bfloat16* kws   = qws + 8388608;   // 64*2048*64
  __hip_bfloat16* vtws  = kws + 8388608;
  __hip_bfloat16* yws   = xb;              // alias: xb dead after QKV GEMM
  // peak ws use: ~72 MB

  k_detect<<<1, 256, 0, stream>>>((const unsigned int*)x, flag);
  k_convert3<<<2048, 256, 0, stream>>>(x, wqkv, wo, (unsigned short*)xb, flag);

  k_gemm_qkv<<<384, 512, 0, stream>>>(xb, wqkvb, qws, kws, vtws);

  k_attn<<<512, 512, 0, stream>>>(qws, kws, vtws, yws);

  dim3 g3(64, 8);
  k_gemm_out<<<g3, 512, 0, stream>>>(yws, wob, d_out, flag);
}

// Round 16
// 188.596 us; speedup vs baseline: 1.2084x; 1.2084x over previous
//
#include <hip/hip_runtime.h>
#include <hip/hip_bf16.h>
#include <stdint.h>

// Fused causal attention block: qkv proj -> flash attention -> out proj.
// B=4 T=2048 C=1024 H=16 HD=64.  All MFMA 16x16x32 bf16, fp32 accum.
// Q pre-scaled by 0.125*log2(e); base-2 softmax via raw v_exp_f32; T13.
// attn: T12 swapped-QK^T in-register softmax + 3-buf counted-vmcnt pipeline.
// GEMMs (R16): 4-wave 128^2 blocks, 2-buf 32KB LDS -> 4-5 independent
// blocks/CU (independent barrier domains hide the per-step serial chain);
// prefetch issued at loop top AFTER the barrier (full-iteration flight,
// race-free: barrier(t) passed => all waves done reading buf(t-1)=buf(t+1)).

typedef __attribute__((ext_vector_type(8))) short short8;
typedef __attribute__((ext_vector_type(4))) float f32x4;
typedef __attribute__((ext_vector_type(4))) float float4v;
typedef __attribute__((ext_vector_type(4))) unsigned short ushort4v;
typedef __attribute__((ext_vector_type(4))) unsigned int u32x4;

#define AS1 __attribute__((address_space(1)))
#define AS3 __attribute__((address_space(3)))

#if __has_builtin(__builtin_amdgcn_exp2f)
#define EXP2(x) __builtin_amdgcn_exp2f(x)
#else
#define EXP2(x) __expf((x) * 0.69314718f)
#endif

static __device__ __forceinline__ void gload_lds16(const void* g, void* l) {
  __builtin_amdgcn_global_load_lds((const AS1 void*)g, (AS3 void*)l, 16, 0, 0);
}

// ---------------- dtype detect ----------------
__global__ void k_detect(const unsigned int* __restrict__ x, int* __restrict__ flag) {
  __shared__ int sm[256];
  int c = 0;
  for (int i = 0; i < 8; ++i) {
    unsigned int v = x[threadIdx.x * 8 + i];
    unsigned int e = (v >> 7) & 0xffu;
    if (e >= 110u && e <= 140u) c++;
  }
  sm[threadIdx.x] = c;
  __syncthreads();
  if (threadIdx.x == 0) {
    int t = 0;
    for (int i = 0; i < 256; ++i) t += sm[i];
    *flag = (t > 1024) ? 1 : 0;   // 1 = inputs are bf16, 0 = fp32
  }
}

// ---------------- fused convert: x | wqkv | wo -> contiguous bf16 ws ----------------
__global__ void k_convert3(const void* __restrict__ xs, const void* __restrict__ wqs,
                           const void* __restrict__ wos, unsigned short* __restrict__ out,
                           const int* __restrict__ flag) {
  const int f = *flag;
  const int stride = gridDim.x * blockDim.x;
  for (int v = blockIdx.x * blockDim.x + threadIdx.x; v < 3145728; v += stride) {
    const int i = v * 4;
    const void* src; int j;
    if (i < 8388608)        { src = xs;  j = i; }
    else if (i < 11534336)  { src = wqs; j = i - 8388608; }
    else                    { src = wos; j = i - 11534336; }
    ushort4v r;
    if (f) {
      r = *(const ushort4v*)((const unsigned short*)src + j);
    } else {
      float4v fv = *(const float4v*)((const float*)src + j);
#pragma unroll
      for (int e = 0; e < 4; e++) {
        __hip_bfloat16 h = __float2bfloat16(fv[e]);
        r[e] = *(unsigned short*)&h;
      }
    }
    *(ushort4v*)(out + i) = r;
  }
}

// ---------------- stage 1: QKV GEMM (4 waves, 2-buf, issue-at-top) ----------------
// 256 threads, wave tile 64x64, acc[4][4]: 16 MFMA + 8 ds_read/wave/step.
// Iteration: vmcnt(0, own tile-t loads) -> s_barrier -> issue t+1 into
// buf^1 -> ds_read+MFMA from buf. 32KB LDS -> 4-5 blocks/CU, independent
// barrier domains. LDS chunk swizzle: pos p of row r holds chunk p^((r>>1)&3).
__global__ __launch_bounds__(256) void k_gemm_qkv(
    const __hip_bfloat16* __restrict__ X, const __hip_bfloat16* __restrict__ W,
    __hip_bfloat16* __restrict__ qo, __hip_bfloat16* __restrict__ ko,
    __hip_bfloat16* __restrict__ vto) {
  __shared__ __align__(16) __hip_bfloat16 As[2][128 * 32];
  __shared__ __align__(16) __hip_bfloat16 Bs[2][128 * 32];
  const int tid = threadIdx.x;
  const int lane = tid & 63;
  const int wid = tid >> 6;
  const int wr = wid >> 1, wc = wid & 1;
  const int lr = lane & 15, lk = lane >> 4;
  const int m0 = blockIdx.x * 128;
  const int n0 = blockIdx.y * 128;
  const int sw = (lr >> 1) & 3;              // lane-uniform s(r) for reads

  // staging geometry: 2 chunks per thread per matrix
  const int row0 = tid >> 2,          row1 = (256 + tid) >> 2;
  const int ce0 = ((tid & 3) ^ ((row0 >> 1) & 3)) * 8;
  const int ce1 = ((tid & 3) ^ ((row1 >> 1) & 3)) * 8;
  const int d0 = (tid & ~63) * 8, d1 = (256 + (tid & ~63)) * 8;

  const f32x4 fzero = {0.f, 0.f, 0.f, 0.f};
  f32x4 acc[4][4];
#pragma unroll
  for (int i = 0; i < 4; i++)
#pragma unroll
    for (int j = 0; j < 4; j++) acc[i][j] = fzero;

#define QKV_STAGE(buf, kt2)                                                     \
  {                                                                             \
    const int kk = (kt2) * 32;                                                  \
    gload_lds16(X + (size_t)(m0 + row0) * 1024 + kk + ce0, (void*)(As[buf] + d0)); \
    gload_lds16(W + (size_t)(n0 + row0) * 1024 + kk + ce0, (void*)(Bs[buf] + d0)); \
    gload_lds16(X + (size_t)(m0 + row1) * 1024 + kk + ce1, (void*)(As[buf] + d1)); \
    gload_lds16(W + (size_t)(n0 + row1) * 1024 + kk + ce1, (void*)(Bs[buf] + d1)); \
  }

  QKV_STAGE(0, 0)

  int cur = 0;
  for (int kt = 0; kt < 32; ++kt) {
    // own tile-t loads are the only outstanding ones here
    asm volatile("s_waitcnt vmcnt(0)" ::: "memory");
    __builtin_amdgcn_s_barrier();
    __builtin_amdgcn_sched_barrier(0);
    // issue next tile now: flies during this tile's compute (full flight)
    if (kt + 1 < 32) { QKV_STAGE(cur ^ 1, kt + 1) }

    short8 a[4], b[4];
#pragma unroll
    for (int i = 0; i < 4; i++) a[i] = *(const short8*)(As[cur] + (wr * 64 + i * 16 + lr) * 32 + ((lk ^ sw) * 8));
#pragma unroll
    for (int i = 0; i < 4; i++) b[i] = *(const short8*)(Bs[cur] + (wc * 64 + i * 16 + lr) * 32 + ((lk ^ sw) * 8));
#pragma unroll
    for (int mf = 0; mf < 4; mf++)
#pragma unroll
      for (int nf = 0; nf < 4; nf++)
        acc[mf][nf] = __builtin_amdgcn_mfma_f32_16x16x32_bf16(a[mf], b[nf], acc[mf][nf], 0, 0, 0);

    cur ^= 1;
  }
#undef QKV_STAGE

#pragma unroll
  for (int mf = 0; mf < 4; mf++)
#pragma unroll
    for (int nf = 0; nf < 4; nf++)
#pragma unroll
      for (int r = 0; r < 4; r++) {
        const int orow = m0 + wr * 64 + mf * 16 + lk * 4 + r;  // b*T+t
        const int col = n0 + wc * 64 + nf * 16 + lr;           // [0,3072)
        const int s = col >> 10;
        const int rem = col & 1023;
        const int h = rem >> 6, hd = rem & 63;
        const int bb = orow >> 11, t = orow & 2047;
        const size_t bh = (size_t)(bb * 16 + h);
        if (s == 0) {
          // pre-scale Q by 0.125 * log2(e): softmax runs in base-2 domain
          qo[(bh * 2048 + t) * 64 + hd] = __float2bfloat16(acc[mf][nf][r] * 0.18033688f);
        } else if (s == 1) {
          ko[(bh * 2048 + t) * 64 + hd] = __float2bfloat16(acc[mf][nf][r]);
        } else {
          vto[(bh * 64 + hd) * 2048 + t] = __float2bfloat16(acc[mf][nf][r]);
        }
      }
}

// ---------------- stage 2: flash attention (T12 swapped QK^T) ----------------
// 512 blocks x 512 threads (8 waves). Q-tile 256 rows (32/wave). KV tile 64.
// bh = bid&63, p = bid>>6 mapped so CU pairs (e,7-e) have equal totals.
// 3 LDS KV buffers, issue 2 ahead, counted vmcnt(2).
// Swapped QK^T: C = mfma(A=K, B=Q) -> lane owns one q (col=lr), 16 k's.
// A-row permutation f(a,i) = (i>>2)*8 + (a&1)*4 + (i&3) + (a>>1)*32 makes
// lane lk's C regs = exactly k = {lk*8..+7} (+32) -> PV B-frag is built
// IN-LANE (no LDS P, no cross-lane moves). Softmax: 2 shfl per q-group
// (max only); l-sum deferred per-lane to epilogue. O comes out transposed
// -> LDS transpose epilogue (bank-XOR'd) -> coalesced 16B Y stores.
// LDS swizzle F(r) = (r&7) ^ (2*(r>>3) & 7) keeps kb/vb reads uniform.
__global__ __launch_bounds__(512) void k_attn(
    const __hip_bfloat16* __restrict__ Q, const __hip_bfloat16* __restrict__ K,
    const __hip_bfloat16* __restrict__ VT, __hip_bfloat16* __restrict__ Y) {
  __shared__ __align__(16) char smem[49152];   // K bufs 0..2 | V bufs 0..2
  char* smc = smem;
  const int tid = threadIdx.x, lane = tid & 63, wid = tid >> 6;
  const int lr = lane & 15, lk = lane >> 4;

  const int bid = blockIdx.x;
  const int bh = bid & 63;
  const int p = bid >> 6;            // 0..7
  const int e = p & 3;
  const int x = (p < 4) ? p : 7 - e; // CU gets {e, 7-e}: 36 tiles total
  const int q0 = x * 256;
  const int qb = q0 + wid * 32;
  const size_t base = (size_t)bh * 2048 * 64;

  // staging: 512 chunks of 16B per 64x64 tile, source pre-swizzled by F
  const int srow = tid >> 3;                        // 0..63
  const int fs = (srow & 7) ^ ((2 * (srow >> 3)) & 7);
  const int scol = ((tid & 7) ^ fs) * 8;
  const __hip_bfloat16* kg = K + base + scol;
  const __hip_bfloat16* vg = VT + base + (size_t)srow * 2048 + scol;
  const int ldst = (tid & ~63) * 16;                // wave-uniform LDS dest

  // per-lane read offsets (bytes within an 8KB buffer)
  int koff[4][2], voff[4][2], kla[4];
#pragma unroll
  for (int a = 0; a < 4; a++) {
    const int ra = (lr >> 2) * 8 + (a & 1) * 4 + (lr & 3) + (a >> 1) * 32;
    const int fr = (ra & 7) ^ ((2 * (ra >> 3)) & 7);
    kla[a] = lk * 8 + (a & 1) * 4 + (a >> 1) * 32;
#pragma unroll
    for (int ks = 0; ks < 2; ks++)
      koff[a][ks] = ra * 128 + (((ks * 4 + lk) ^ fr) * 16);
  }
#pragma unroll
  for (int df = 0; df < 4; df++) {
    const int rv = df * 16 + lr;
    const int fv = (rv & 7) ^ ((2 * (rv >> 3)) & 7);
#pragma unroll
    for (int ks = 0; ks < 2; ks++)
      voff[df][ks] = rv * 128 + (((ks * 4 + lk) ^ fv) * 16);
  }

  short8 qf[2][2];
#pragma unroll
  for (int qg = 0; qg < 2; qg++)
#pragma unroll
    for (int ks = 0; ks < 2; ks++)
      qf[qg][ks] = *(const short8*)(Q + base + (size_t)(qb + qg * 16 + lr) * 64 + ks * 32 + lk * 8);

  const f32x4 fzero = {0.f, 0.f, 0.f, 0.f};
  f32x4 ot[2][4];                     // O^T accum: row d, col q
  float mrow[2] = {-1e30f, -1e30f}, lrow[2] = {0.f, 0.f};
#pragma unroll
  for (int qg = 0; qg < 2; qg++)
#pragma unroll
    for (int df = 0; df < 4; df++) ot[qg][df] = fzero;

  const int nkv = x * 4 + 4;
  // prologue: stage tiles 0,1 into bufs 0,1
  gload_lds16(kg + (size_t)srow * 64, (void*)(smc + ldst));
  gload_lds16(vg, (void*)(smc + 24576 + ldst));
  gload_lds16(kg + (size_t)(64 + srow) * 64, (void*)(smc + 8192 + ldst));
  gload_lds16(vg + 64, (void*)(smc + 24576 + 8192 + ldst));

  int cur = 0;
  for (int kt = 0; kt < nkv; ++kt) {
    const int k0 = kt * 64;
    if (kt + 1 < nkv) { asm volatile("s_waitcnt vmcnt(2)" ::: "memory"); }
    else              { asm volatile("s_waitcnt vmcnt(0)" ::: "memory"); }
    __builtin_amdgcn_s_barrier();
    __builtin_amdgcn_sched_barrier(0);

    if (k0 <= qb + 31) {   // wave-uniform: skip fully-masked tiles
      const char* kbuf = smc + cur * 8192;
      const char* vbuf = smc + 24576 + cur * 8192;

      f32x4 s[2][4];
#pragma unroll
      for (int qg = 0; qg < 2; qg++)
#pragma unroll
        for (int a = 0; a < 4; a++) s[qg][a] = fzero;

      __builtin_amdgcn_s_setprio(1);
#pragma unroll
      for (int ks = 0; ks < 2; ks++)
#pragma unroll
        for (int a = 0; a < 4; a++) {
          const short8 kb = *(const short8*)(kbuf + koff[a][ks]);
          s[0][a] = __builtin_amdgcn_mfma_f32_16x16x32_bf16(kb, qf[0][ks], s[0][a], 0, 0, 0);
          s[1][a] = __builtin_amdgcn_mfma_f32_16x16x32_bf16(kb, qf[1][ks], s[1][a], 0, 0, 0);
        }
      __builtin_amdgcn_s_setprio(0);

      const bool needmask = (k0 + 63 > qb);
      short8 pb[2][2];

#pragma unroll
      for (int qg = 0; qg < 2; qg++) {
        const int qq = qb + qg * 16 + lr;
        if (needmask) {
#pragma unroll
          for (int a = 0; a < 4; a++)
#pragma unroll
            for (int r = 0; r < 4; r++)
              if (k0 + kla[a] + r > qq) s[qg][a][r] = -1e30f;
        }
        // in-lane max over 16, then 2 shfl across lk groups
        f32x4 m4;
#pragma unroll
        for (int r = 0; r < 4; r++)
          m4[r] = fmaxf(fmaxf(s[qg][0][r], s[qg][1][r]), fmaxf(s[qg][2][r], s[qg][3][r]));
        float mx = fmaxf(fmaxf(m4[0], m4[1]), fmaxf(m4[2], m4[3]));
        mx = fmaxf(mx, __shfl_xor(mx, 16, 64));
        mx = fmaxf(mx, __shfl_xor(mx, 32, 64));
        const float mold = mrow[qg];
        float m;
        if (__all(mx - mold <= 8.f)) {
          m = mold;            // T13 defer: P bounded by 2^8
        } else {
          m = fmaxf(mold, mx);
          const float alpha = EXP2(mold - m);
          lrow[qg] *= alpha;
          mrow[qg] = m;
#pragma unroll
          for (int df = 0; df < 4; df++) ot[qg][df] *= alpha;
        }
        float rs = 0.f;
#pragma unroll
        for (int a = 0; a < 4; a++)
#pragma unroll
          for (int r = 0; r < 4; r++) {
            const float pv = EXP2(s[qg][a][r] - m);
            s[qg][a][r] = pv;
            rs += pv;
          }
        lrow[qg] += rs;        // per-lane partial; cross-lane at epilogue
        // pack PV B-frags: e<4 from block 2ksP, e>=4 from 2ksP+1 (in-lane!)
#pragma unroll
        for (int ksP = 0; ksP < 2; ksP++) {
          short8 w;
#pragma unroll
          for (int ee = 0; ee < 4; ee++) {
            __hip_bfloat16 h0 = __float2bfloat16(s[qg][2 * ksP][ee]);
            __hip_bfloat16 h1 = __float2bfloat16(s[qg][2 * ksP + 1][ee]);
            w[ee] = *(short*)&h0;
            w[4 + ee] = *(short*)&h1;
          }
          pb[qg][ksP] = w;
        }
      }

      // PV: o^T[d][q] += V^T[d][k] * P[k][q]
      __builtin_amdgcn_s_setprio(1);
#pragma unroll
      for (int ks = 0; ks < 2; ks++)
#pragma unroll
        for (int df = 0; df < 4; df++) {
          const short8 vb = *(const short8*)(vbuf + voff[df][ks]);
          ot[0][df] = __builtin_amdgcn_mfma_f32_16x16x32_bf16(vb, pb[0][ks], ot[0][df], 0, 0, 0);
          ot[1][df] = __builtin_amdgcn_mfma_f32_16x16x32_bf16(vb, pb[1][ks], ot[1][df], 0, 0, 0);
        }
      __builtin_amdgcn_s_setprio(0);
    }

    // issue tile kt+2 into buf (cur+2)%3 AFTER compute (3-buf race-freedom)
    if (kt + 2 < nkv) {
      const int kn = (kt + 2) * 64;
      int tb = cur + 2; if (tb >= 3) tb -= 3;
      gload_lds16(kg + (size_t)(kn + srow) * 64, (void*)(smc + tb * 8192 + ldst));
      gload_lds16(vg + kn, (void*)(smc + 24576 + tb * 8192 + ldst));
    }
    cur = (cur + 1 == 3) ? 0 : cur + 1;
  }

  // ---- epilogue: normalize, transpose through LDS, coalesced store ----
  __syncthreads();                      // all waves done with K/V buffers
  unsigned int* Os = (unsigned int*)smc; // 256 rows x 32 u32 = 32 KB
#pragma unroll
  for (int qg = 0; qg < 2; qg++) {
    float ls = lrow[qg];
    ls += __shfl_xor(ls, 16, 64);
    ls += __shfl_xor(ls, 32, 64);
    const float inv = 1.f / ls;
    const int qlocal = wid * 32 + qg * 16 + lr;
    const int sw = (lr & 7) << 2;
#pragma unroll
    for (int df = 0; df < 4; df++)
#pragma unroll
      for (int e2 = 0; e2 < 2; e2++) {
        __hip_bfloat16 h0 = __float2bfloat16(ot[qg][df][2 * e2] * inv);
        __hip_bfloat16 h1 = __float2bfloat16(ot[qg][df][2 * e2 + 1] * inv);
        const unsigned int w = (unsigned int)*(unsigned short*)&h0 |
                               ((unsigned int)*(unsigned short*)&h1 << 16);
        Os[qlocal * 32 + ((df * 8 + lk * 2 + e2) ^ sw)] = w;
      }
  }
  __syncthreads();
  {
    const int qrow = tid >> 1, half = tid & 1, q7 = qrow & 7;
    const int b = bh >> 4, h = bh & 15;
    unsigned int* Yu = (unsigned int*)Y;
    const size_t rowbase = ((size_t)b * 2048 + q0 + qrow) * 512 + h * 32;
#pragma unroll
    for (int g = 0; g < 4; g++) {
      const int cg = half * 4 + g;
      const u32x4 v = *(const u32x4*)(smc + qrow * 128 + ((cg ^ q7) * 16));
      *(u32x4*)(Yu + rowbase + cg * 4) = v;
    }
  }
}

// ---------------- stage 3: output GEMM (4 waves, 2-buf, issue-at-top) ----------------
__global__ __launch_bounds__(256) void k_gemm_out(
    const __hip_bfloat16* __restrict__ X, const __hip_bfloat16* __restrict__ W,
    void* __restrict__ out, const int* __restrict__ flag) {
  __shared__ __align__(16) __hip_bfloat16 As[2][128 * 32];
  __shared__ __align__(16) __hip_bfloat16 Bs[2][128 * 32];
  const int tid = threadIdx.x;
  const int lane = tid & 63;
  const int wid = tid >> 6;
  const int wr = wid >> 1, wc = wid & 1;
  const int lr = lane & 15, lk = lane >> 4;
  const int m0 = blockIdx.x * 128;
  const int n0 = blockIdx.y * 128;
  const int sw = (lr >> 1) & 3;

  const int row0 = tid >> 2,          row1 = (256 + tid) >> 2;
  const int ce0 = ((tid & 3) ^ ((row0 >> 1) & 3)) * 8;
  const int ce1 = ((tid & 3) ^ ((row1 >> 1) & 3)) * 8;
  const int d0 = (tid & ~63) * 8, d1 = (256 + (tid & ~63)) * 8;

  const f32x4 fzero = {0.f, 0.f, 0.f, 0.f};
  f32x4 acc[4][4];
#pragma unroll
  for (int i = 0; i < 4; i++)
#pragma unroll
    for (int j = 0; j < 4; j++) acc[i][j] = fzero;

#define OUT_STAGE(buf, kt2)                                                     \
  {                                                                             \
    const int kk = (kt2) * 32;                                                  \
    gload_lds16(X + (size_t)(m0 + row0) * 1024 + kk + ce0, (void*)(As[buf] + d0)); \
    gload_lds16(W + (size_t)(n0 + row0) * 1024 + kk + ce0, (void*)(Bs[buf] + d0)); \
    gload_lds16(X + (size_t)(m0 + row1) * 1024 + kk + ce1, (void*)(As[buf] + d1)); \
    gload_lds16(W + (size_t)(n0 + row1) * 1024 + kk + ce1, (void*)(Bs[buf] + d1)); \
  }

  OUT_STAGE(0, 0)

  int cur = 0;
  for (int kt = 0; kt < 32; ++kt) {
    asm volatile("s_waitcnt vmcnt(0)" ::: "memory");
    __builtin_amdgcn_s_barrier();
    __builtin_amdgcn_sched_barrier(0);
    if (kt + 1 < 32) { OUT_STAGE(cur ^ 1, kt + 1) }

    short8 a[4], b[4];
#pragma unroll
    for (int i = 0; i < 4; i++) a[i] = *(const short8*)(As[cur] + (wr * 64 + i * 16 + lr) * 32 + ((lk ^ sw) * 8));
#pragma unroll
    for (int i = 0; i < 4; i++) b[i] = *(const short8*)(Bs[cur] + (wc * 64 + i * 16 + lr) * 32 + ((lk ^ sw) * 8));
#pragma unroll
    for (int mf = 0; mf < 4; mf++)
#pragma unroll
      for (int nf = 0; nf < 4; nf++)
        acc[mf][nf] = __builtin_amdgcn_mfma_f32_16x16x32_bf16(a[mf], b[nf], acc[mf][nf], 0, 0, 0);

    cur ^= 1;
  }
#undef OUT_STAGE

  const int f = *flag;
#pragma unroll
  for (int mf = 0; mf < 4; mf++)
#pragma unroll
    for (int nf = 0; nf < 4; nf++)
#pragma unroll
      for (int r = 0; r < 4; r++) {
        const int orow = m0 + wr * 64 + mf * 16 + lk * 4 + r;
        const int col = n0 + wc * 64 + nf * 16 + lr;
        const size_t oi = (size_t)orow * 1024 + col;
        if (f) ((__hip_bfloat16*)out)[oi] = __float2bfloat16(acc[mf][nf][r]);
        else   ((float*)out)[oi] = acc[mf][nf][r];
      }
}

// ---------------- launch ----------------
extern "C" void kernel_launch(void* const* d_in, const int* in_sizes, int n_in,
                              void* d_out, int out_size, void* d_ws, size_t ws_size,
                              hipStream_t stream) {
  const void* x = d_in[0];     // [4,2048,1024]
  const void* wqkv = d_in[1];  // [3072,1024]
  const void* wo = d_in[2];    // [1024,1024]

  char* ws = (char*)d_ws;
  int* flag = (int*)ws;
  __hip_bfloat16* xb    = (__hip_bfloat16*)(ws + 256);
  __hip_bfloat16* wqkvb = xb + 8388608;
  __hip_bfloat16* wob   = wqkvb + 3145728;
  __hip_bfloat16* qws   = wob + 1048576;
  __hip_bfloat16* kws   = qws + 8388608;   // 64*2048*64
  __hip_bfloat16* vtws  = kws + 8388608;
  __hip_bfloat16* yws   = xb;              // alias: xb dead after QKV GEMM
  // peak ws use: ~72 MB

  k_detect<<<1, 256, 0, stream>>>((const unsigned int*)x, flag);
  k_convert3<<<2048, 256, 0, stream>>>(x, wqkv, wo, (unsigned short*)xb, flag);

  dim3 g1(64, 24);
  k_gemm_qkv<<<g1, 256, 0, stream>>>(xb, wqkvb, qws, kws, vtws);

  k_attn<<<512, 512, 0, stream>>>(qws, kws, vtws, yws);

  dim3 g3(64, 8);
  k_gemm_out<<<g3, 256, 0, stream>>>(yws, wob, d_out, flag);
}

// Round 17
// 178.514 us; speedup vs baseline: 1.2766x; 1.0565x over previous
//
#include <hip/hip_runtime.h>
#include <hip/hip_bf16.h>
#include <stdint.h>

// Fused causal attention block: qkv proj -> flash attention -> out proj.
// B=4 T=2048 C=1024 H=16 HD=64.  All MFMA 16x16x32 bf16, fp32 accum.
// Q pre-scaled by 0.125*log2(e); base-2 softmax via raw v_exp_f32; T13.
// attn: T12 swapped-QK^T in-register softmax + 3-buf counted-vmcnt pipeline.
// qkv GEMM: 128x256 block tile, wave tile 64x64, 16 MFMA/wave/step (R14).
// (R17 = revert to R14, the session's best verified configuration.)

typedef __attribute__((ext_vector_type(8))) short short8;
typedef __attribute__((ext_vector_type(4))) float f32x4;
typedef __attribute__((ext_vector_type(4))) float float4v;
typedef __attribute__((ext_vector_type(4))) unsigned short ushort4v;
typedef __attribute__((ext_vector_type(4))) unsigned int u32x4;

#define AS1 __attribute__((address_space(1)))
#define AS3 __attribute__((address_space(3)))

#if __has_builtin(__builtin_amdgcn_exp2f)
#define EXP2(x) __builtin_amdgcn_exp2f(x)
#else
#define EXP2(x) __expf((x) * 0.69314718f)
#endif

static __device__ __forceinline__ void gload_lds16(const void* g, void* l) {
  __builtin_amdgcn_global_load_lds((const AS1 void*)g, (AS3 void*)l, 16, 0, 0);
}

// ---------------- dtype detect ----------------
__global__ void k_detect(const unsigned int* __restrict__ x, int* __restrict__ flag) {
  __shared__ int sm[256];
  int c = 0;
  for (int i = 0; i < 8; ++i) {
    unsigned int v = x[threadIdx.x * 8 + i];
    unsigned int e = (v >> 7) & 0xffu;
    if (e >= 110u && e <= 140u) c++;
  }
  sm[threadIdx.x] = c;
  __syncthreads();
  if (threadIdx.x == 0) {
    int t = 0;
    for (int i = 0; i < 256; ++i) t += sm[i];
    *flag = (t > 1024) ? 1 : 0;   // 1 = inputs are bf16, 0 = fp32
  }
}

// ---------------- fused convert: x | wqkv | wo -> contiguous bf16 ws ----------------
__global__ void k_convert3(const void* __restrict__ xs, const void* __restrict__ wqs,
                           const void* __restrict__ wos, unsigned short* __restrict__ out,
                           const int* __restrict__ flag) {
  const int f = *flag;
  const int stride = gridDim.x * blockDim.x;
  for (int v = blockIdx.x * blockDim.x + threadIdx.x; v < 3145728; v += stride) {
    const int i = v * 4;
    const void* src; int j;
    if (i < 8388608)        { src = xs;  j = i; }
    else if (i < 11534336)  { src = wqs; j = i - 8388608; }
    else                    { src = wos; j = i - 11534336; }
    ushort4v r;
    if (f) {
      r = *(const ushort4v*)((const unsigned short*)src + j);
    } else {
      float4v fv = *(const float4v*)((const float*)src + j);
#pragma unroll
      for (int e = 0; e < 4; e++) {
        __hip_bfloat16 h = __float2bfloat16(fv[e]);
        r[e] = *(unsigned short*)&h;
      }
    }
    *(ushort4v*)(out + i) = r;
  }
}

// ---------------- stage 1: QKV GEMM (8 waves, 128x256 tile, 3-buf vmcnt) ----------------
// Wave tile 64x64: wm=wid&1 (m half), wn=wid>>1 (n quarter). 16 MFMA +
// 8 ds_read_b128 per wave per K-step. Staging: A 1 chunk/thread, B 2
// chunks/thread -> 3 gload_lds/tile -> vmcnt(3) steady (2-ahead).
// LDS chunk swizzle: position p of row r holds global chunk p ^ ((r>>1)&3).
__global__ __launch_bounds__(512) void k_gemm_qkv(
    const __hip_bfloat16* __restrict__ X, const __hip_bfloat16* __restrict__ W,
    __hip_bfloat16* __restrict__ qo, __hip_bfloat16* __restrict__ ko,
    __hip_bfloat16* __restrict__ vto) {
  __shared__ __align__(16) __hip_bfloat16 As[3][128 * 32];
  __shared__ __align__(16) __hip_bfloat16 Bs[3][256 * 32];
  const int tid = threadIdx.x;
  const int lane = tid & 63;
  const int wid = tid >> 6;
  const int wr = wid & 1, wc = wid >> 1;
  const int lr = lane & 15, lk = lane >> 4;
  const int m0 = blockIdx.x * 128;
  const int n0 = blockIdx.y * 256;
  const int sw = (lr >> 1) & 3;              // lane-uniform s(r) for reads

  // staging geometry: A 512 chunks (1/thread), B 1024 chunks (2/thread)
  const int rowa = tid >> 2;                 // 0..127
  const int cea = ((tid & 3) ^ ((rowa >> 1) & 3)) * 8;
  const int rowb1 = 128 + rowa;
  const int ceb1 = ((tid & 3) ^ ((rowb1 >> 1) & 3)) * 8;
  const int dsta = (tid & ~63) * 8;
  const int dstb1 = (512 + (tid & ~63)) * 8;

  const f32x4 fzero = {0.f, 0.f, 0.f, 0.f};
  f32x4 acc[4][4];
#pragma unroll
  for (int i = 0; i < 4; i++)
#pragma unroll
    for (int j = 0; j < 4; j++) acc[i][j] = fzero;

#define QKV_STAGE(buf, kt2)                                                          \
  {                                                                                  \
    const int kk = (kt2) * 32;                                                       \
    gload_lds16(X + (size_t)(m0 + rowa) * 1024 + kk + cea, (void*)(As[buf] + dsta)); \
    gload_lds16(W + (size_t)(n0 + rowa) * 1024 + kk + cea, (void*)(Bs[buf] + dsta)); \
    gload_lds16(W + (size_t)(n0 + rowb1) * 1024 + kk + ceb1, (void*)(Bs[buf] + dstb1)); \
  }

  QKV_STAGE(0, 0)
  QKV_STAGE(1, 1)

  int cur = 0;
  for (int kt = 0; kt < 32; ++kt) {
    if (kt + 1 < 32) { asm volatile("s_waitcnt vmcnt(3)" ::: "memory"); }
    else             { asm volatile("s_waitcnt vmcnt(0)" ::: "memory"); }
    __builtin_amdgcn_s_barrier();
    __builtin_amdgcn_sched_barrier(0);

    short8 a[4], b[4];
#pragma unroll
    for (int i = 0; i < 4; i++) a[i] = *(const short8*)(As[cur] + (wr * 64 + i * 16 + lr) * 32 + ((lk ^ sw) * 8));
#pragma unroll
    for (int i = 0; i < 4; i++) b[i] = *(const short8*)(Bs[cur] + (wc * 64 + i * 16 + lr) * 32 + ((lk ^ sw) * 8));
#pragma unroll
    for (int mf = 0; mf < 4; mf++)
#pragma unroll
      for (int nf = 0; nf < 4; nf++)
        acc[mf][nf] = __builtin_amdgcn_mfma_f32_16x16x32_bf16(a[mf], b[nf], acc[mf][nf], 0, 0, 0);

    if (kt + 2 < 32) {
      int tb = cur + 2; if (tb >= 3) tb -= 3;
      QKV_STAGE(tb, kt + 2)
    }
    cur = (cur + 1 == 3) ? 0 : cur + 1;
  }
#undef QKV_STAGE

#pragma unroll
  for (int mf = 0; mf < 4; mf++)
#pragma unroll
    for (int nf = 0; nf < 4; nf++)
#pragma unroll
      for (int r = 0; r < 4; r++) {
        const int orow = m0 + wr * 64 + mf * 16 + lk * 4 + r;  // b*T+t
        const int col = n0 + wc * 64 + nf * 16 + lr;           // [0,3072)
        const int s = col >> 10;
        const int rem = col & 1023;
        const int h = rem >> 6, hd = rem & 63;
        const int bb = orow >> 11, t = orow & 2047;
        const size_t bh = (size_t)(bb * 16 + h);
        if (s == 0) {
          // pre-scale Q by 0.125 * log2(e): softmax runs in base-2 domain
          qo[(bh * 2048 + t) * 64 + hd] = __float2bfloat16(acc[mf][nf][r] * 0.18033688f);
        } else if (s == 1) {
          ko[(bh * 2048 + t) * 64 + hd] = __float2bfloat16(acc[mf][nf][r]);
        } else {
          vto[(bh * 64 + hd) * 2048 + t] = __float2bfloat16(acc[mf][nf][r]);
        }
      }
}

// ---------------- stage 2: flash attention (T12 swapped QK^T) ----------------
// 512 blocks x 512 threads (8 waves). Q-tile 256 rows (32/wave). KV tile 64.
// bh = bid&63, p = bid>>6 mapped so CU pairs (e,7-e) have equal totals.
// 3 LDS KV buffers, issue 2 ahead, counted vmcnt(2).
// Swapped QK^T: C = mfma(A=K, B=Q) -> lane owns one q (col=lr), 16 k's.
// A-row permutation f(a,i) = (i>>2)*8 + (a&1)*4 + (i&3) + (a>>1)*32 makes
// lane lk's C regs = exactly k = {lk*8..+7} (+32) -> PV B-frag is built
// IN-LANE (no LDS P, no cross-lane moves). Softmax: 2 shfl per q-group
// (max only); l-sum deferred per-lane to epilogue. O comes out transposed
// -> LDS transpose epilogue (bank-XOR'd) -> coalesced 16B Y stores.
// LDS swizzle F(r) = (r&7) ^ (2*(r>>3) & 7) keeps kb/vb reads uniform.
__global__ __launch_bounds__(512) void k_attn(
    const __hip_bfloat16* __restrict__ Q, const __hip_bfloat16* __restrict__ K,
    const __hip_bfloat16* __restrict__ VT, __hip_bfloat16* __restrict__ Y) {
  __shared__ __align__(16) char smem[49152];   // K bufs 0..2 | V bufs 0..2
  char* smc = smem;
  const int tid = threadIdx.x, lane = tid & 63, wid = tid >> 6;
  const int lr = lane & 15, lk = lane >> 4;

  const int bid = blockIdx.x;
  const int bh = bid & 63;
  const int p = bid >> 6;            // 0..7
  const int e = p & 3;
  const int x = (p < 4) ? p : 7 - e; // CU gets {e, 7-e}: 36 tiles total
  const int q0 = x * 256;
  const int qb = q0 + wid * 32;
  const size_t base = (size_t)bh * 2048 * 64;

  // staging: 512 chunks of 16B per 64x64 tile, source pre-swizzled by F
  const int srow = tid >> 3;                        // 0..63
  const int fs = (srow & 7) ^ ((2 * (srow >> 3)) & 7);
  const int scol = ((tid & 7) ^ fs) * 8;
  const __hip_bfloat16* kg = K + base + scol;
  const __hip_bfloat16* vg = VT + base + (size_t)srow * 2048 + scol;
  const int ldst = (tid & ~63) * 16;                // wave-uniform LDS dest

  // per-lane read offsets (bytes within an 8KB buffer)
  int koff[4][2], voff[4][2], kla[4];
#pragma unroll
  for (int a = 0; a < 4; a++) {
    const int ra = (lr >> 2) * 8 + (a & 1) * 4 + (lr & 3) + (a >> 1) * 32;
    const int fr = (ra & 7) ^ ((2 * (ra >> 3)) & 7);
    kla[a] = lk * 8 + (a & 1) * 4 + (a >> 1) * 32;
#pragma unroll
    for (int ks = 0; ks < 2; ks++)
      koff[a][ks] = ra * 128 + (((ks * 4 + lk) ^ fr) * 16);
  }
#pragma unroll
  for (int df = 0; df < 4; df++) {
    const int rv = df * 16 + lr;
    const int fv = (rv & 7) ^ ((2 * (rv >> 3)) & 7);
#pragma unroll
    for (int ks = 0; ks < 2; ks++)
      voff[df][ks] = rv * 128 + (((ks * 4 + lk) ^ fv) * 16);
  }

  short8 qf[2][2];
#pragma unroll
  for (int qg = 0; qg < 2; qg++)
#pragma unroll
    for (int ks = 0; ks < 2; ks++)
      qf[qg][ks] = *(const short8*)(Q + base + (size_t)(qb + qg * 16 + lr) * 64 + ks * 32 + lk * 8);

  const f32x4 fzero = {0.f, 0.f, 0.f, 0.f};
  f32x4 ot[2][4];                     // O^T accum: row d, col q
  float mrow[2] = {-1e30f, -1e30f}, lrow[2] = {0.f, 0.f};
#pragma unroll
  for (int qg = 0; qg < 2; qg++)
#pragma unroll
    for (int df = 0; df < 4; df++) ot[qg][df] = fzero;

  const int nkv = x * 4 + 4;
  // prologue: stage tiles 0,1 into bufs 0,1
  gload_lds16(kg + (size_t)srow * 64, (void*)(smc + ldst));
  gload_lds16(vg, (void*)(smc + 24576 + ldst));
  gload_lds16(kg + (size_t)(64 + srow) * 64, (void*)(smc + 8192 + ldst));
  gload_lds16(vg + 64, (void*)(smc + 24576 + 8192 + ldst));

  int cur = 0;
  for (int kt = 0; kt < nkv; ++kt) {
    const int k0 = kt * 64;
    if (kt + 1 < nkv) { asm volatile("s_waitcnt vmcnt(2)" ::: "memory"); }
    else              { asm volatile("s_waitcnt vmcnt(0)" ::: "memory"); }
    __builtin_amdgcn_s_barrier();
    __builtin_amdgcn_sched_barrier(0);

    if (k0 <= qb + 31) {   // wave-uniform: skip fully-masked tiles
      const char* kbuf = smc + cur * 8192;
      const char* vbuf = smc + 24576 + cur * 8192;

      f32x4 s[2][4];
#pragma unroll
      for (int qg = 0; qg < 2; qg++)
#pragma unroll
        for (int a = 0; a < 4; a++) s[qg][a] = fzero;

      __builtin_amdgcn_s_setprio(1);
#pragma unroll
      for (int ks = 0; ks < 2; ks++)
#pragma unroll
        for (int a = 0; a < 4; a++) {
          const short8 kb = *(const short8*)(kbuf + koff[a][ks]);
          s[0][a] = __builtin_amdgcn_mfma_f32_16x16x32_bf16(kb, qf[0][ks], s[0][a], 0, 0, 0);
          s[1][a] = __builtin_amdgcn_mfma_f32_16x16x32_bf16(kb, qf[1][ks], s[1][a], 0, 0, 0);
        }
      __builtin_amdgcn_s_setprio(0);

      const bool needmask = (k0 + 63 > qb);
      short8 pb[2][2];

#pragma unroll
      for (int qg = 0; qg < 2; qg++) {
        const int qq = qb + qg * 16 + lr;
        if (needmask) {
#pragma unroll
          for (int a = 0; a < 4; a++)
#pragma unroll
            for (int r = 0; r < 4; r++)
              if (k0 + kla[a] + r > qq) s[qg][a][r] = -1e30f;
        }
        // in-lane max over 16, then 2 shfl across lk groups
        f32x4 m4;
#pragma unroll
        for (int r = 0; r < 4; r++)
          m4[r] = fmaxf(fmaxf(s[qg][0][r], s[qg][1][r]), fmaxf(s[qg][2][r], s[qg][3][r]));
        float mx = fmaxf(fmaxf(m4[0], m4[1]), fmaxf(m4[2], m4[3]));
        mx = fmaxf(mx, __shfl_xor(mx, 16, 64));
        mx = fmaxf(mx, __shfl_xor(mx, 32, 64));
        const float mold = mrow[qg];
        float m;
        if (__all(mx - mold <= 8.f)) {
          m = mold;            // T13 defer: P bounded by 2^8
        } else {
          m = fmaxf(mold, mx);
          const float alpha = EXP2(mold - m);
          lrow[qg] *= alpha;
          mrow[qg] = m;
#pragma unroll
          for (int df = 0; df < 4; df++) ot[qg][df] *= alpha;
        }
        float rs = 0.f;
#pragma unroll
        for (int a = 0; a < 4; a++)
#pragma unroll
          for (int r = 0; r < 4; r++) {
            const float pv = EXP2(s[qg][a][r] - m);
            s[qg][a][r] = pv;
            rs += pv;
          }
        lrow[qg] += rs;        // per-lane partial; cross-lane at epilogue
        // pack PV B-frags: e<4 from block 2ksP, e>=4 from 2ksP+1 (in-lane!)
#pragma unroll
        for (int ksP = 0; ksP < 2; ksP++) {
          short8 w;
#pragma unroll
          for (int ee = 0; ee < 4; ee++) {
            __hip_bfloat16 h0 = __float2bfloat16(s[qg][2 * ksP][ee]);
            __hip_bfloat16 h1 = __float2bfloat16(s[qg][2 * ksP + 1][ee]);
            w[ee] = *(short*)&h0;
            w[4 + ee] = *(short*)&h1;
          }
          pb[qg][ksP] = w;
        }
      }

      // PV: o^T[d][q] += V^T[d][k] * P[k][q]
      __builtin_amdgcn_s_setprio(1);
#pragma unroll
      for (int ks = 0; ks < 2; ks++)
#pragma unroll
        for (int df = 0; df < 4; df++) {
          const short8 vb = *(const short8*)(vbuf + voff[df][ks]);
          ot[0][df] = __builtin_amdgcn_mfma_f32_16x16x32_bf16(vb, pb[0][ks], ot[0][df], 0, 0, 0);
          ot[1][df] = __builtin_amdgcn_mfma_f32_16x16x32_bf16(vb, pb[1][ks], ot[1][df], 0, 0, 0);
        }
      __builtin_amdgcn_s_setprio(0);
    }

    // issue tile kt+2 into buf (cur+2)%3 AFTER compute (3-buf race-freedom)
    if (kt + 2 < nkv) {
      const int kn = (kt + 2) * 64;
      int tb = cur + 2; if (tb >= 3) tb -= 3;
      gload_lds16(kg + (size_t)(kn + srow) * 64, (void*)(smc + tb * 8192 + ldst));
      gload_lds16(vg + kn, (void*)(smc + 24576 + tb * 8192 + ldst));
    }
    cur = (cur + 1 == 3) ? 0 : cur + 1;
  }

  // ---- epilogue: normalize, transpose through LDS, coalesced store ----
  __syncthreads();                      // all waves done with K/V buffers
  unsigned int* Os = (unsigned int*)smc; // 256 rows x 32 u32 = 32 KB
#pragma unroll
  for (int qg = 0; qg < 2; qg++) {
    float ls = lrow[qg];
    ls += __shfl_xor(ls, 16, 64);
    ls += __shfl_xor(ls, 32, 64);
    const float inv = 1.f / ls;
    const int qlocal = wid * 32 + qg * 16 + lr;
    const int sw = (lr & 7) << 2;
#pragma unroll
    for (int df = 0; df < 4; df++)
#pragma unroll
      for (int e2 = 0; e2 < 2; e2++) {
        __hip_bfloat16 h0 = __float2bfloat16(ot[qg][df][2 * e2] * inv);
        __hip_bfloat16 h1 = __float2bfloat16(ot[qg][df][2 * e2 + 1] * inv);
        const unsigned int w = (unsigned int)*(unsigned short*)&h0 |
                               ((unsigned int)*(unsigned short*)&h1 << 16);
        Os[qlocal * 32 + ((df * 8 + lk * 2 + e2) ^ sw)] = w;
      }
  }
  __syncthreads();
  {
    const int qrow = tid >> 1, half = tid & 1, q7 = qrow & 7;
    const int b = bh >> 4, h = bh & 15;
    unsigned int* Yu = (unsigned int*)Y;
    const size_t rowbase = ((size_t)b * 2048 + q0 + qrow) * 512 + h * 32;
#pragma unroll
    for (int g = 0; g < 4; g++) {
      const int cg = half * 4 + g;
      const u32x4 v = *(const u32x4*)(smc + qrow * 128 + ((cg ^ q7) * 16));
      *(u32x4*)(Yu + rowbase + cg * 4) = v;
    }
  }
}

// ---------------- stage 3: output GEMM (8 waves, 3-buf counted vmcnt) ----------------
__global__ __launch_bounds__(512) void k_gemm_out(
    const __hip_bfloat16* __restrict__ X, const __hip_bfloat16* __restrict__ W,
    void* __restrict__ out, const int* __restrict__ flag) {
  __shared__ __align__(16) __hip_bfloat16 As[3][128 * 32];
  __shared__ __align__(16) __hip_bfloat16 Bs[3][128 * 32];
  const int tid = threadIdx.x;
  const int lane = tid & 63;
  const int wid = tid >> 6;
  const int wr = wid & 3, wc = wid >> 2;
  const int lr = lane & 15, lk = lane >> 4;
  const int m0 = blockIdx.x * 128;
  const int n0 = blockIdx.y * 128;
  const int sw = (lr >> 1) & 3;

  const int row = tid >> 2;
  const int ce = ((tid & 3) ^ ((row >> 1) & 3)) * 8;
  const int dst = (tid & ~63) * 8;

  const f32x4 fzero = {0.f, 0.f, 0.f, 0.f};
  f32x4 acc[2][4];
#pragma unroll
  for (int i = 0; i < 2; i++)
#pragma unroll
    for (int j = 0; j < 4; j++) acc[i][j] = fzero;

#define OUT_STAGE(buf, kt2)                                                        \
  {                                                                                \
    const int kk = (kt2) * 32;                                                     \
    gload_lds16(X + (size_t)(m0 + row) * 1024 + kk + ce, (void*)(As[buf] + dst));  \
    gload_lds16(W + (size_t)(n0 + row) * 1024 + kk + ce, (void*)(Bs[buf] + dst));  \
  }

  OUT_STAGE(0, 0)
  OUT_STAGE(1, 1)

  int cur = 0;
  for (int kt = 0; kt < 32; ++kt) {
    if (kt + 1 < 32) { asm volatile("s_waitcnt vmcnt(2)" ::: "memory"); }
    else             { asm volatile("s_waitcnt vmcnt(0)" ::: "memory"); }
    __builtin_amdgcn_s_barrier();
    __builtin_amdgcn_sched_barrier(0);

    short8 a[2], b[4];
#pragma unroll
    for (int i = 0; i < 2; i++) a[i] = *(const short8*)(As[cur] + (wr * 32 + i * 16 + lr) * 32 + ((lk ^ sw) * 8));
#pragma unroll
    for (int i = 0; i < 4; i++) b[i] = *(const short8*)(Bs[cur] + (wc * 64 + i * 16 + lr) * 32 + ((lk ^ sw) * 8));
#pragma unroll
    for (int mf = 0; mf < 2; mf++)
#pragma unroll
      for (int nf = 0; nf < 4; nf++)
        acc[mf][nf] = __builtin_amdgcn_mfma_f32_16x16x32_bf16(a[mf], b[nf], acc[mf][nf], 0, 0, 0);

    if (kt + 2 < 32) {
      int tb = cur + 2; if (tb >= 3) tb -= 3;
      OUT_STAGE(tb, kt + 2)
    }
    cur = (cur + 1 == 3) ? 0 : cur + 1;
  }
#undef OUT_STAGE

  const int f = *flag;
#pragma unroll
  for (int mf = 0; mf < 2; mf++)
#pragma unroll
    for (int nf = 0; nf < 4; nf++)
#pragma unroll
      for (int r = 0; r < 4; r++) {
        const int orow = m0 + wr * 32 + mf * 16 + lk * 4 + r;
        const int col = n0 + wc * 64 + nf * 16 + lr;
        const size_t oi = (size_t)orow * 1024 + col;
        if (f) ((__hip_bfloat16*)out)[oi] = __float2bfloat16(acc[mf][nf][r]);
        else   ((float*)out)[oi] = acc[mf][nf][r];
      }
}

// ---------------- launch ----------------
extern "C" void kernel_launch(void* const* d_in, const int* in_sizes, int n_in,
                              void* d_out, int out_size, void* d_ws, size_t ws_size,
                              hipStream_t stream) {
  const void* x = d_in[0];     // [4,2048,1024]
  const void* wqkv = d_in[1];  // [3072,1024]
  const void* wo = d_in[2];    // [1024,1024]

  char* ws = (char*)d_ws;
  int* flag = (int*)ws;
  __hip_bfloat16* xb    = (__hip_bfloat16*)(ws + 256);
  __hip_bfloat16* wqkvb = xb + 8388608;
  __hip_bfloat16* wob   = wqkvb + 3145728;
  __hip_bfloat16* qws   = wob + 1048576;
  __hip_bfloat16* kws   = qws + 8388608;   // 64*2048*64
  __hip_bfloat16* vtws  = kws + 8388608;
  __hip_bfloat16* yws   = xb;              // alias: xb dead after QKV GEMM
  // peak ws use: ~72 MB

  k_detect<<<1, 256, 0, stream>>>((const unsigned int*)x, flag);
  k_convert3<<<2048, 256, 0, stream>>>(x, wqkv, wo, (unsigned short*)xb, flag);

  dim3 g1(64, 12);
  k_gemm_qkv<<<g1, 512, 0, stream>>>(xb, wqkvb, qws, kws, vtws);

  k_attn<<<512, 512, 0, stream>>>(qws, kws, vtws, yws);

  dim3 g3(64, 8);
  k_gemm_out<<<g3, 512, 0, stream>>>(yws, wob, d_out, flag);
}